// Round 6
// baseline (2202.597 us; speedup 1.0000x reference)
//
#include <hip/hip_runtime.h>
#include <math.h>

#define BATCH  128
#define NENT   256
#define INDIM  256
#define HID    512
#define NHEAD  8
#define NAGENT 64
#define SCALE  0.04419417382415922f   // 1/sqrt(512)

// Chunked split-bf16 layout (DMA-friendly, conflict-free LDS reads):
// A 32-k (or 32-e) block for 16 rows is one 2 KB chunk:
//   [hi: q(4) x row16(16) x 8 u16][lo: same]   (1 KB hi + 1 KB lo)
// Single-precision chunks (value path) are 1 KB: [q][row16][8 u16].
// Frag read for lane (l15=row, quad=q): 16 B at q*256B + l15*16B  -> 2-way (free).
// h_c:   [rowtile 2048][kblk 16][2KB]  = 64 MB
// Mt_c:  [n][dtile 32][kblk 16][2KB]   = 8 MB
// WVt_c: [n][dntile 32][kblk 16][1KB]  = 4 MB
// hT_c:  [b][dtile 32][eblk 8][1KB]    = 32 MB (optional, ws>=108MB)

typedef unsigned short u16;
typedef unsigned int   u32;

typedef __bf16 bf16x8  __attribute__((ext_vector_type(8)));
typedef float  floatx4 __attribute__((ext_vector_type(4)));
typedef u32    u32x4   __attribute__((ext_vector_type(4)));
typedef u32    u32x2   __attribute__((ext_vector_type(2)));

union Frag {
    u32x4 s;
    struct { u32x2 lo, hi; } p;
    bf16x8 v;
};

#define MFMA(a, b, c) __builtin_amdgcn_mfma_f32_16x16x32_bf16((a), (b), (c), 0, 0, 0)
#define VMW(n) (((n) & 0xF) | (0xF << 8) | (0x7 << 4))

__device__ __forceinline__ void gld16(const u16* g, u16* l) {
    __builtin_amdgcn_global_load_lds(
        (const __attribute__((address_space(1))) void*)g,
        (__attribute__((address_space(3))) void*)l, 16, 0, 0);
}

__device__ __forceinline__ u16 f2bf(float x) {
    u32 u = __float_as_uint(x);
    return (u16)((u + 0x7FFFu + ((u >> 16) & 1u)) >> 16);
}
__device__ __forceinline__ float bf2f(u16 b) {
    return __uint_as_float(((u32)b) << 16);
}
__device__ __forceinline__ void split4(const float4& r, ushort4& hh, ushort4& hl) {
    hh.x = f2bf(r.x); hl.x = f2bf(r.x - bf2f(hh.x));
    hh.y = f2bf(r.y); hl.y = f2bf(r.y - bf2f(hh.y));
    hh.z = f2bf(r.z); hl.z = f2bf(r.z - bf2f(hh.z));
    hh.w = f2bf(r.w); hl.w = f2bf(r.w - bf2f(hh.w));
}
// chunk u16-offset of element (row, col) in hi part; lo = +512 (2KB chunks)
__device__ __forceinline__ size_t chunk_off(int row16, int col) {
    return (size_t)((col >> 3) & 3) * 128 + (size_t)row16 * 8 + (col & 7);
}

// -----------------------------------------------------------------------------
// K0: Wt_p[d][k] = packed split(W_enc[k][d]) (transpose), R5 layout kept
// -----------------------------------------------------------------------------
__global__ __launch_bounds__(256) void wenc_t_kernel(const float* __restrict__ W,
                                                     u16* __restrict__ Wt_p) {
    __shared__ float tile[64][68];
    const int bid = blockIdx.x;
    const int k0 = (bid & 3) * 64;
    const int d0 = (bid >> 2) * 64;
    const int t = threadIdx.x;
    const int ki = t >> 2, dc = (t & 3) * 16;
    #pragma unroll
    for (int c = 0; c < 4; ++c)
        *(float4*)&tile[ki][dc + c * 4] =
            *(const float4*)(W + (size_t)(k0 + ki) * HID + d0 + dc + c * 4);
    __syncthreads();
    const int dr = t >> 2, kc = (t & 3) * 16;
    #pragma unroll
    for (int c = 0; c < 4; ++c) {
        float4 v = make_float4(tile[kc + c * 4 + 0][dr], tile[kc + c * 4 + 1][dr],
                               tile[kc + c * 4 + 2][dr], tile[kc + c * 4 + 3][dr]);
        ushort4 hh, hl; split4(v, hh, hl);
        const int kk = k0 + kc + c * 4;
        size_t o = (size_t)(d0 + dr) * 512 + (size_t)(kk >> 5) * 64 + (kk & 31);
        *(ushort4*)(Wt_p + o) = hh;
        *(ushort4*)(Wt_p + o + 32) = hl;
    }
}

// -----------------------------------------------------------------------------
// K1: h = leaky_relu(x)@W_enc + b  -> h_c chunked layout
// -----------------------------------------------------------------------------
__global__ __launch_bounds__(256) void enc_kernel(const float* __restrict__ x,
                                                  const u16* __restrict__ Wt_p,
                                                  const float* __restrict__ bias,
                                                  u16* __restrict__ hC) {
    __shared__ u16 Ah[32][264];
    __shared__ u16 Al[32][264];
    const int r0 = blockIdx.x * 32;
    const int t  = threadIdx.x;
    {
        const int row = t >> 3;
        const float* xr = x + (size_t)(r0 + row) * INDIM;
        #pragma unroll
        for (int j = 0; j < 8; ++j) {
            const int k0 = ((t & 7) + j * 8) * 4;
            float4 v = *(const float4*)(xr + k0);
            v.x = v.x > 0.f ? v.x : 0.01f * v.x;
            v.y = v.y > 0.f ? v.y : 0.01f * v.y;
            v.z = v.z > 0.f ? v.z : 0.01f * v.z;
            v.w = v.w > 0.f ? v.w : 0.01f * v.w;
            ushort4 hh, hl; split4(v, hh, hl);
            *(ushort4*)&Ah[row][k0] = hh;
            *(ushort4*)&Al[row][k0] = hl;
        }
    }
    __syncthreads();

    const int wid = t >> 6, lane = t & 63, l15 = lane & 15, quad = lane >> 4;
    const int mbase = (wid & 1) * 16;
    const int nbase = (wid >> 1) * 256;
    const floatx4 z4 = {0.f, 0.f, 0.f, 0.f};
    floatx4 acc[16];
    #pragma unroll
    for (int i = 0; i < 16; ++i) acc[i] = z4;

    for (int ks = 0; ks < 8; ++ks) {
        const int k = ks * 32 + quad * 8;
        Frag Afh, Afl;
        Afh.s = *(const u32x4*)&Ah[mbase + l15][k];
        Afl.s = *(const u32x4*)&Al[mbase + l15][k];
        #pragma unroll
        for (int nt = 0; nt < 16; ++nt) {
            const int d = nbase + nt * 16 + l15;
            const size_t wo = (size_t)d * 512 + (size_t)ks * 64 + quad * 8;
            Frag Bh, Bl;
            Bh.s = *(const u32x4*)(Wt_p + wo);
            Bl.s = *(const u32x4*)(Wt_p + wo + 32);
            floatx4 c = acc[nt];
            c = MFMA(Afh.v, Bh.v, c);
            c = MFMA(Afh.v, Bl.v, c);
            c = MFMA(Afl.v, Bh.v, c);
            acc[nt] = c;
        }
    }
    #pragma unroll
    for (int nt = 0; nt < 16; ++nt) {
        const int d = nbase + nt * 16 + l15;
        const float bv = bias[d];
        #pragma unroll
        for (int r = 0; r < 4; ++r) {
            const float v = acc[nt][r] + bv;
            const u16 hi = f2bf(v);
            const u16 lo = f2bf(v - bf2f(hi));
            const int row = r0 + mbase + quad * 4 + r;
            const size_t o = (size_t)((row >> 4) * 16 + (d >> 5)) * 1024
                           + chunk_off(row & 15, d);
            hC[o]       = hi;
            hC[o + 512] = lo;
        }
    }
}

// -----------------------------------------------------------------------------
// K1b: hT_c[b][dtile][eblk] chunks = transpose of hi(h)
// -----------------------------------------------------------------------------
__global__ __launch_bounds__(256) void ht_kernel(const u16* __restrict__ hC,
                                                 u16* __restrict__ hTC) {
    __shared__ u16 tile[64][72];
    const int bid = blockIdx.x;               // 8 dt64 x 4 et64 x 128 b
    const int dt64 = bid & 7;
    const int et64 = (bid >> 3) & 3;
    const int b    = bid >> 5;
    const int t    = threadIdx.x;
    const int r  = t >> 2, cs = (t & 3) * 16;
    const int row = b * 256 + et64 * 64 + r;
    #pragma unroll
    for (int c = 0; c < 4; ++c) {
        const int d0 = dt64 * 64 + cs + c * 4;
        const size_t o = (size_t)((row >> 4) * 16 + (d0 >> 5)) * 1024
                       + chunk_off(row & 15, d0);
        *(ushort4*)&tile[r][cs + c * 4] = *(const ushort4*)(hC + o);
    }
    __syncthreads();
    const int dr = t >> 2, es = (t & 3) * 16;
    const int dg = dt64 * 64 + dr;
    #pragma unroll
    for (int c = 0; c < 4; ++c) {
        const int e = et64 * 64 + es + c * 4;
        ushort4 v = make_ushort4(tile[es + c * 4 + 0][dr], tile[es + c * 4 + 1][dr],
                                 tile[es + c * 4 + 2][dr], tile[es + c * 4 + 3][dr]);
        const size_t o = (size_t)((b * 32 + (dg >> 4)) * 8 + (e >> 5)) * 512
                       + (size_t)((e >> 3) & 3) * 128 + (size_t)(dg & 15) * 8 + (e & 7);
        *(ushort4*)(hTC + o) = v;
    }
}

// -----------------------------------------------------------------------------
// K2: Mt_c chunks = packed split(SCALE * WQ WK^T) (row = d, col = k)
// -----------------------------------------------------------------------------
__global__ __launch_bounds__(256) void wqk_kernel(const float* __restrict__ WQ,
                                                  const float* __restrict__ WK,
                                                  u16* __restrict__ MtC) {
    __shared__ u16 Ah[64][72], Al[64][72], Bh[64][72], Bl[64][72];
    const int bid = blockIdx.x;
    const int jt = (bid & 7) * 64;
    const int it = ((bid >> 3) & 7) * 64;
    const int n  = bid >> 6;
    const float* qp = WQ + (size_t)n * 262144;
    const float* kp = WK + (size_t)n * 262144;
    const int t = threadIdx.x;
    const int wid = t >> 6, lane = t & 63, l15 = lane & 15, quad = lane >> 4;
    const int srow = t >> 2, sc = (t & 3) * 16;

    const floatx4 z4 = {0.f, 0.f, 0.f, 0.f};
    floatx4 acc[4];
    #pragma unroll
    for (int i = 0; i < 4; ++i) acc[i] = z4;

    for (int kc = 0; kc < HID; kc += 64) {
        #pragma unroll
        for (int f = 0; f < 4; ++f) {
            float4 va = *(const float4*)(kp + (size_t)(jt + srow) * HID + kc + sc + f * 4);
            ushort4 hh, hl; split4(va, hh, hl);
            *(ushort4*)&Ah[srow][sc + f * 4] = hh;
            *(ushort4*)&Al[srow][sc + f * 4] = hl;
            float4 vb = *(const float4*)(qp + (size_t)(it + srow) * HID + kc + sc + f * 4);
            split4(vb, hh, hl);
            *(ushort4*)&Bh[srow][sc + f * 4] = hh;
            *(ushort4*)&Bl[srow][sc + f * 4] = hl;
        }
        __syncthreads();
        #pragma unroll
        for (int ks = 0; ks < 2; ++ks) {
            const int k = ks * 32 + quad * 8;
            Frag Afh, Afl;
            Afh.s = *(const u32x4*)&Ah[wid * 16 + l15][k];
            Afl.s = *(const u32x4*)&Al[wid * 16 + l15][k];
            #pragma unroll
            for (int nt = 0; nt < 4; ++nt) {
                Frag Bfh, Bfl;
                Bfh.s = *(const u32x4*)&Bh[nt * 16 + l15][k];
                Bfl.s = *(const u32x4*)&Bl[nt * 16 + l15][k];
                floatx4 c = acc[nt];
                c = MFMA(Afh.v, Bfh.v, c);
                c = MFMA(Afh.v, Bfl.v, c);
                c = MFMA(Afl.v, Bfh.v, c);
                acc[nt] = c;
            }
        }
        __syncthreads();
    }
    #pragma unroll
    for (int nt = 0; nt < 4; ++nt)
        #pragma unroll
        for (int r = 0; r < 4; ++r) {
            const float v = acc[nt][r] * SCALE;
            const u16 hi = f2bf(v);
            const u16 lo = f2bf(v - bf2f(hi));
            const int j = jt + wid * 16 + quad * 4 + r;   // d-row
            const int i = it + nt * 16 + l15;             // k-col
            const size_t o = (size_t)n * 524288
                           + (size_t)((j >> 4) * 16 + (i >> 5)) * 1024
                           + chunk_off(j & 15, i);
            MtC[o]       = hi;
            MtC[o + 512] = lo;
        }
}

// -----------------------------------------------------------------------------
// K3: WVt_c chunks (1KB, hi only): row = dout, col = din
// -----------------------------------------------------------------------------
__global__ __launch_bounds__(256) void wvt_kernel(const float* __restrict__ WV,
                                                  u16* __restrict__ WvC) {
    __shared__ float tile[64][68];
    const int bid = blockIdx.x;
    const int i0 = (bid & 7) * 64;          // din tile
    const int o0 = ((bid >> 3) & 7) * 64;   // dout tile
    const int n  = bid >> 6;
    const float* src = WV + (size_t)n * 262144;
    const int t  = threadIdx.x;
    const int di = t >> 2;
    const int dc = (t & 3) * 16;
    #pragma unroll
    for (int c = 0; c < 4; ++c)
        *(float4*)&tile[di][dc + c * 4] =
            *(const float4*)(src + (size_t)(i0 + di) * HID + o0 + dc + c * 4);
    __syncthreads();
    const int dr = t >> 2;                   // dout-local
    const int ic = (t & 3) * 16;             // din-local base
    const int dn = o0 + dr;
    #pragma unroll
    for (int c = 0; c < 4; ++c) {
        const int k = i0 + ic + c * 4;
        ushort4 v = make_ushort4(f2bf(tile[ic + c * 4 + 0][dr]), f2bf(tile[ic + c * 4 + 1][dr]),
                                 f2bf(tile[ic + c * 4 + 2][dr]), f2bf(tile[ic + c * 4 + 3][dr]));
        const size_t o = (size_t)((n * 32 + (dn >> 4)) * 16 + (k >> 5)) * 512
                       + (size_t)((k >> 3) & 3) * 128 + (size_t)(dn & 15) * 8 + (k & 7);
        *(ushort4*)(WvC + o) = v;
    }
}

// -----------------------------------------------------------------------------
// K4: fused MFMA attention, all streams DMA-staged (global_load_lds),
// wave-private double-buffered pipelines, vmcnt(N) waits.
// LDS map (53504 B, 3 blocks/CU):
//   STG  [0, 32768)      per-wave 8 KB (2 bufs x 4 KB)
//   S    [0, 33792) f32  (after phases A/B)
//   red  [33792, 34816)
//   Uq   [34816, 43264)  [32][132] u16 (phase D quarters)
//   Tq/Pt[36864, 53504)  [32][260] u16 (time-disjoint)
//   HbT  [0, 36864)      fallback phase C only
// -----------------------------------------------------------------------------
template<bool USE_HT>
__global__ __launch_bounds__(256, 3) void attn_kernel(const u16* __restrict__ hC,
                                                      const u16* __restrict__ MtC_g,
                                                      const u16* __restrict__ WvC_g,
                                                      const u16* __restrict__ hTC,
                                                      float* __restrict__ out) {
    __shared__ __align__(16) char SM[53504];
    float* S   = (float*)SM;                  // [256][33]
    float* red = (float*)(SM + 33792);        // [256]
    u16*   Uq  = (u16*)(SM + 34816);          // [32][132]
    u16*   Tq  = (u16*)(SM + 36864);          // [32][260]
    u16*   Pt  = (u16*)(SM + 36864);          // [32][260]
    u16*   HbT = (u16*)SM;                    // [512][36] fallback

    const int bid = blockIdx.x;
    const int x7 = bid & 7;
    const int s  = bid >> 3;
    const int at = s & 1;
    const int n  = (x7 >> 1) | (((s >> 1) & 1) << 2);
    const int b  = ((s >> 2) << 1) | (x7 & 1);

    const int tid  = threadIdx.x;
    const int wid  = tid >> 6;
    const int lane = tid & 63;
    const int l15  = lane & 15;
    const int quad = lane >> 4;

    u16* stg = (u16*)(SM + wid * 8192);       // 2 bufs x 2048 u16

    const u16* MtC = MtC_g + (size_t)n * 524288;
    const u16* WvC = WvC_g + (size_t)n * 262144;
    const int  rtA = b * 16 + at * 2;         // agent row-tile base in hC

    const floatx4 z4 = {0.f, 0.f, 0.f, 0.f};
    floatx4 Sacc[8];
    #pragma unroll
    for (int i = 0; i < 8; ++i) Sacc[i] = z4;

    for (int qtr = 0; qtr < 4; ++qtr) {
        // ======== Phase A: Tq = ha @ Mt[:, qtr*128..+128), K=512 ========
        floatx4 Tacc[4] = {z4, z4, z4, z4};
        Frag Aq[2][4];
        auto dmaA = [&](int ks, int bsel) {
            u16* dst = stg + bsel * 2048;
            #pragma unroll
            for (int nt = 0; nt < 2; ++nt) {
                const u16* src = MtC + (size_t)((qtr * 8 + wid * 2 + nt) * 16 + ks) * 1024;
                gld16(src + lane * 8,       dst + nt * 1024 + lane * 8);
                gld16(src + 512 + lane * 8, dst + nt * 1024 + 512 + lane * 8);
            }
        };
        auto ldA = [&](int ks, Frag* A) {
            #pragma unroll
            for (int mt = 0; mt < 2; ++mt) {
                const u16* src = hC + (size_t)((rtA + mt) * 16 + ks) * 1024
                               + quad * 128 + l15 * 8;
                A[mt * 2 + 0].s = *(const u32x4*)src;
                A[mt * 2 + 1].s = *(const u32x4*)(src + 512);
            }
        };
        dmaA(0, 0);
        __builtin_amdgcn_wave_barrier();
        ldA(0, Aq[0]);
        __builtin_amdgcn_wave_barrier();
        #pragma unroll 2
        for (int ks = 0; ks < 16; ++ks) {
            const int bsel = ks & 1;
            if (ks < 15) {
                dmaA(ks + 1, bsel ^ 1);
                __builtin_amdgcn_wave_barrier();
                ldA(ks + 1, Aq[bsel ^ 1]);
                __builtin_amdgcn_wave_barrier();
                __builtin_amdgcn_s_waitcnt(VMW(8));
            } else {
                __builtin_amdgcn_s_waitcnt(VMW(0));
            }
            __builtin_amdgcn_wave_barrier();
            const u16* buf = stg + bsel * 2048;
            #pragma unroll
            for (int nt = 0; nt < 2; ++nt) {
                Frag Bh, Bl;
                Bh.s = *(const u32x4*)(buf + nt * 1024 + quad * 128 + l15 * 8);
                Bl.s = *(const u32x4*)(buf + nt * 1024 + 512 + quad * 128 + l15 * 8);
                #pragma unroll
                for (int mt = 0; mt < 2; ++mt) {
                    floatx4 c = Tacc[mt * 2 + nt];
                    c = MFMA(Aq[bsel][mt * 2 + 0].v, Bh.v, c);
                    c = MFMA(Aq[bsel][mt * 2 + 0].v, Bl.v, c);
                    c = MFMA(Aq[bsel][mt * 2 + 1].v, Bh.v, c);
                    Tacc[mt * 2 + nt] = c;
                }
            }
        }
        __syncthreads();
        #pragma unroll
        for (int mt = 0; mt < 2; ++mt)
            #pragma unroll
            for (int nt = 0; nt < 2; ++nt)
                #pragma unroll
                for (int r = 0; r < 4; ++r) {
                    const float v = Tacc[mt * 2 + nt][r];
                    const int a   = mt * 16 + quad * 4 + r;
                    const int col = (wid * 2 + nt) * 16 + l15;
                    const u16 hi = f2bf(v);
                    Tq[a * 260 + (col >> 5) * 64 + (col & 31)]      = hi;
                    Tq[a * 260 + (col >> 5) * 64 + (col & 31) + 32] = f2bf(v - bf2f(hi));
                }
        __syncthreads();
        // ======== Phase B: S^T += hb[:, qtr] @ Tq^T (4 ks x 2 halves) ========
        auto dmaB = [&](int st, int bsel) {
            const int ks = st >> 1, h = st & 1;
            u16* dst = stg + bsel * 2048;
            #pragma unroll
            for (int i = 0; i < 2; ++i) {
                const int rt = b * 16 + wid * 4 + h * 2 + i;
                const u16* src = hC + (size_t)(rt * 16 + qtr * 4 + ks) * 1024;
                gld16(src + lane * 8,       dst + i * 1024 + lane * 8);
                gld16(src + 512 + lane * 8, dst + i * 1024 + 512 + lane * 8);
            }
        };
        dmaB(0, 0);
        #pragma unroll 2
        for (int st = 0; st < 8; ++st) {
            const int bsel = st & 1;
            if (st < 7) {
                dmaB(st + 1, bsel ^ 1);
                __builtin_amdgcn_s_waitcnt(VMW(4));
            } else {
                __builtin_amdgcn_s_waitcnt(VMW(0));
            }
            __builtin_amdgcn_wave_barrier();
            const int ks = st >> 1, h = st & 1;
            const u16* buf = stg + bsel * 2048;
            Frag Ahf[2], Alf[2];
            #pragma unroll
            for (int i = 0; i < 2; ++i) {
                Ahf[i].s = *(const u32x4*)(buf + i * 1024 + quad * 128 + l15 * 8);
                Alf[i].s = *(const u32x4*)(buf + i * 1024 + 512 + quad * 128 + l15 * 8);
            }
            #pragma unroll
            for (int nt = 0; nt < 2; ++nt) {
                const int ac = nt * 16 + l15;
                Frag Bfh, Bfl;
                Bfh.p.lo = *(const u32x2*)(Tq + ac * 260 + ks * 64 + quad * 8);
                Bfh.p.hi = *(const u32x2*)(Tq + ac * 260 + ks * 64 + quad * 8 + 4);
                Bfl.p.lo = *(const u32x2*)(Tq + ac * 260 + ks * 64 + quad * 8 + 32);
                Bfl.p.hi = *(const u32x2*)(Tq + ac * 260 + ks * 64 + quad * 8 + 36);
                #pragma unroll
                for (int i = 0; i < 2; ++i) {
                    floatx4 c = Sacc[(h * 2 + i) * 2 + nt];
                    c = MFMA(Ahf[i].v, Bfh.v, c);
                    c = MFMA(Ahf[i].v, Bfl.v, c);
                    c = MFMA(Alf[i].v, Bfh.v, c);
                    Sacc[(h * 2 + i) * 2 + nt] = c;
                }
            }
        }
        __syncthreads();
    }
    // ======== S to LDS + softmax ========
    #pragma unroll
    for (int mt = 0; mt < 4; ++mt)
        #pragma unroll
        for (int nt = 0; nt < 2; ++nt)
            #pragma unroll
            for (int r = 0; r < 4; ++r) {
                const int e = (wid * 4 + mt) * 16 + quad * 4 + r;
                const int a = nt * 16 + l15;
                S[e * 33 + a] = Sacc[mt * 2 + nt][r];
            }
    __syncthreads();
    {
        const int a   = tid & 31;
        const int seg = tid >> 5;
        float v[32];
        #pragma unroll
        for (int i = 0; i < 32; ++i) v[i] = S[(seg * 32 + i) * 33 + a];
        float mx = v[0];
        #pragma unroll
        for (int i = 1; i < 32; ++i) mx = fmaxf(mx, v[i]);
        red[a * 8 + seg] = mx;
        __syncthreads();
        float gmx = red[a * 8 + 0];
        #pragma unroll
        for (int i = 1; i < 8; ++i) gmx = fmaxf(gmx, red[a * 8 + i]);
        __syncthreads();
        float sum = 0.f;
        #pragma unroll
        for (int i = 0; i < 32; ++i) { v[i] = expf(v[i] - gmx); sum += v[i]; }
        red[a * 8 + seg] = sum;
        __syncthreads();
        float tot = 0.f;
        #pragma unroll
        for (int i = 0; i < 8; ++i) tot += red[a * 8 + i];
        const float inv = 1.0f / tot;
        #pragma unroll
        for (int i = 0; i < 32; ++i)
            Pt[a * 260 + seg * 32 + i] = f2bf(v[i] * inv);
    }
    __syncthreads();
    // ======== Phase C: U = P @ hb ========
    floatx4 Uacc[16];
    #pragma unroll
    for (int i = 0; i < 16; ++i) Uacc[i] = z4;
    const int d0w = wid * 128;
    if (USE_HT) {
        auto dmaC = [&](int st, int bsel) {
            const int et = st >> 1, h = st & 1;
            u16* dst = stg + bsel * 2048;
            #pragma unroll
            for (int i = 0; i < 4; ++i) {
                const u16* src = hTC + (size_t)((b * 32 + wid * 8 + h * 4 + i) * 8 + et) * 512;
                gld16(src + lane * 8, dst + i * 512 + lane * 8);
            }
        };
        dmaC(0, 0);
        #pragma unroll 2
        for (int st = 0; st < 16; ++st) {
            const int bsel = st & 1;
            if (st < 15) {
                dmaC(st + 1, bsel ^ 1);
                __builtin_amdgcn_s_waitcnt(VMW(4));
            } else {
                __builtin_amdgcn_s_waitcnt(VMW(0));
            }
            __builtin_amdgcn_wave_barrier();
            const int et = st >> 1, h = st & 1;
            const u16* buf = stg + bsel * 2048;
            Frag Ap[2];
            #pragma unroll
            for (int mt = 0; mt < 2; ++mt) {
                const int ar = mt * 16 + l15;
                Ap[mt].p.lo = *(const u32x2*)(Pt + ar * 260 + et * 32 + quad * 8);
                Ap[mt].p.hi = *(const u32x2*)(Pt + ar * 260 + et * 32 + quad * 8 + 4);
            }
            #pragma unroll
            for (int i = 0; i < 4; ++i) {
                Frag Bf;
                Bf.s = *(const u32x4*)(buf + i * 512 + quad * 128 + l15 * 8);
                #pragma unroll
                for (int mt = 0; mt < 2; ++mt)
                    Uacc[mt * 8 + h * 4 + i] = MFMA(Ap[mt].v, Bf.v, Uacc[mt * 8 + h * 4 + i]);
            }
        }
    } else {
        // fallback: in-LDS pair-packed transpose from hC (hi halves)
        u32* Hb32 = (u32*)HbT;
        for (int et = 0; et < 8; ++et) {
            {
                const int epi = lane & 15;
                const int q8  = lane >> 4;
                #pragma unroll
                for (int c = 0; c < 4; ++c) {
                    const int d0 = d0w + c * 32 + q8 * 8;
                    const int row0 = et * 32 + 2 * epi;
                    const size_t o0 = (size_t)((b * 16 + (row0 >> 4)) * 16 + (d0 >> 5)) * 1024
                                    + chunk_off(row0 & 15, d0);
                    const int row1 = row0 + 1;
                    const size_t o1 = (size_t)((b * 16 + (row1 >> 4)) * 16 + (d0 >> 5)) * 1024
                                    + chunk_off(row1 & 15, d0);
                    u32x4 u0 = *(const u32x4*)(hC + o0);
                    u32x4 u1 = *(const u32x4*)(hC + o1);
                    #pragma unroll
                    for (int p = 0; p < 4; ++p) {
                        const u32 w0 = (u0[p] & 0xFFFFu) | (u1[p] << 16);
                        const u32 w1 = (u0[p] >> 16) | (u1[p] & 0xFFFF0000u);
                        Hb32[(d0 + 2 * p) * 18 + epi]     = w0;
                        Hb32[(d0 + 2 * p + 1) * 18 + epi] = w1;
                    }
                }
            }
            Frag Ap[2];
            #pragma unroll
            for (int mt = 0; mt < 2; ++mt) {
                const int ar = mt * 16 + l15;
                Ap[mt].p.lo = *(const u32x2*)(Pt + ar * 260 + et * 32 + quad * 8);
                Ap[mt].p.hi = *(const u32x2*)(Pt + ar * 260 + et * 32 + quad * 8 + 4);
            }
            #pragma unroll
            for (int dt = 0; dt < 8; ++dt) {
                const int d = d0w + dt * 16 + l15;
                Frag Bf;
                Bf.p.lo = *(const u32x2*)(HbT + d * 36 + quad * 8);
                Bf.p.hi = *(const u32x2*)(HbT + d * 36 + quad * 8 + 4);
                #pragma unroll
                for (int mt = 0; mt < 2; ++mt)
                    Uacc[mt * 8 + dt] = MFMA(Ap[mt].v, Bf.v, Uacc[mt * 8 + dt]);
            }
        }
    }
    // ======== Phase D: z = U @ WVt, per-wave U quarters ========
    floatx4 Zacc[16];
    #pragma unroll
    for (int i = 0; i < 16; ++i) Zacc[i] = z4;
    for (int qq = 0; qq < 4; ++qq) {
        __syncthreads();
        if (wid == qq) {
            #pragma unroll
            for (int mt = 0; mt < 2; ++mt)
                #pragma unroll
                for (int dt = 0; dt < 8; ++dt)
                    #pragma unroll
                    for (int r = 0; r < 4; ++r) {
                        const int a   = mt * 16 + quad * 4 + r;
                        const int col = dt * 16 + l15;
                        Uq[a * 132 + col] = f2bf(Uacc[mt * 8 + dt][r]);
                    }
        }
        __syncthreads();
        auto dmaD = [&](int st, int bsel) {
            const int ksl = st >> 1, h = st & 1;
            u16* dst = stg + bsel * 2048;
            #pragma unroll
            for (int i = 0; i < 4; ++i) {
                const u16* src = WvC + (size_t)((wid * 8 + h * 4 + i) * 16 + qq * 4 + ksl) * 512;
                gld16(src + lane * 8, dst + i * 512 + lane * 8);
            }
        };
        dmaD(0, 0);
        #pragma unroll 2
        for (int st = 0; st < 8; ++st) {
            const int bsel = st & 1;
            if (st < 7) {
                dmaD(st + 1, bsel ^ 1);
                __builtin_amdgcn_s_waitcnt(VMW(4));
            } else {
                __builtin_amdgcn_s_waitcnt(VMW(0));
            }
            __builtin_amdgcn_wave_barrier();
            const int ksl = st >> 1, h = st & 1;
            const u16* buf = stg + bsel * 2048;
            Frag Au[2];
            #pragma unroll
            for (int mt = 0; mt < 2; ++mt) {
                const int ar = mt * 16 + l15;
                Au[mt].p.lo = *(const u32x2*)(Uq + ar * 132 + ksl * 32 + quad * 8);
                Au[mt].p.hi = *(const u32x2*)(Uq + ar * 132 + ksl * 32 + quad * 8 + 4);
            }
            #pragma unroll
            for (int i = 0; i < 4; ++i) {
                Frag Bf;
                Bf.s = *(const u32x4*)(buf + i * 512 + quad * 128 + l15 * 8);
                #pragma unroll
                for (int mt = 0; mt < 2; ++mt)
                    Zacc[mt * 8 + h * 4 + i] = MFMA(Au[mt].v, Bf.v, Zacc[mt * 8 + h * 4 + i]);
            }
        }
    }
    float* ob = out + ((size_t)b * NAGENT + at * 32) * HID;
    #pragma unroll
    for (int mt = 0; mt < 2; ++mt)
        #pragma unroll
        for (int dt = 0; dt < 8; ++dt)
            #pragma unroll
            for (int r = 0; r < 4; ++r) {
                const int a  = mt * 16 + quad * 4 + r;
                const int dn = (wid * 8 + dt) * 16 + l15;
                atomicAdd(ob + (size_t)a * HID + dn, Zacc[mt * 8 + dt][r] * 0.125f);
            }
}

// -----------------------------------------------------------------------------
// ws: h_c [0,64M) | Mt_c [64,72) | WVt_c [72,76) | hT_c [76,108) optional
// -----------------------------------------------------------------------------
extern "C" void kernel_launch(void* const* d_in, const int* in_sizes, int n_in,
                              void* d_out, int out_size, void* d_ws, size_t ws_size,
                              hipStream_t stream) {
    const float* x     = (const float*)d_in[0];
    const float* W_enc = (const float*)d_in[1];
    const float* b_enc = (const float*)d_in[2];
    const float* WQ    = (const float*)d_in[3];
    const float* WK    = (const float*)d_in[4];
    const float* WV    = (const float*)d_in[5];
    float* out = (float*)d_out;

    char* ws = (char*)d_ws;
    u16* hC   = (u16*)ws;
    u16* MtC  = (u16*)(ws + 67108864);
    u16* WvC  = (u16*)(ws + 75497472);
    u16* hTC  = (u16*)(ws + 79691776);
    u16* Wt_p = WvC;                       // transient, 512 KB

    const bool useHT = ws_size >= (size_t)113246208;  // 108 MB

    hipMemsetAsync(d_out, 0, (size_t)out_size * sizeof(float), stream);
    wenc_t_kernel<<<32, 256, 0, stream>>>(W_enc, Wt_p);
    enc_kernel<<<1024, 256, 0, stream>>>(x, Wt_p, b_enc, hC);
    if (useHT) ht_kernel<<<4096, 256, 0, stream>>>(hC, hTC);
    wvt_kernel<<<512, 256, 0, stream>>>(WV, WvC);
    wqk_kernel<<<512, 256, 0, stream>>>(WQ, WK, MtC);
    if (useHT)
        attn_kernel<true><<<2048, 256, 0, stream>>>(hC, MtC, WvC, hTC, out);
    else
        attn_kernel<false><<<2048, 256, 0, stream>>>(hC, MtC, WvC, hTC, out);
}